// Round 1
// baseline (570.105 us; speedup 1.0000x reference)
//
#include <hip/hip_runtime.h>
#include <hip/hip_bf16.h>

#define T_SEQ 2048
#define NBATCH 4
#define NHEAD 16
#define HDIM 64
#define DMODEL 1024

typedef __bf16 bf16x8 __attribute__((ext_vector_type(8)));
typedef float f32x4 __attribute__((ext_vector_type(4)));

__device__ __forceinline__ unsigned short f2bf(float f) {
  unsigned int u = __builtin_bit_cast(unsigned int, f);
  u += 0x7fffu + ((u >> 16) & 1u);
  return (unsigned short)(u >> 16);
}

__device__ __forceinline__ void async_cp16(void* lds, const void* g) {
  __builtin_amdgcn_global_load_lds((const __attribute__((address_space(1))) void*)g,
                                   (__attribute__((address_space(3))) void*)lds,
                                   16, 0, 0);
}

// ---------------- fp32 -> bf16 convert (vectorized) ----------------
__global__ __launch_bounds__(256) void conv_bf16_k(const float* __restrict__ in,
                                                   unsigned short* __restrict__ out, int n) {
  int i = (blockIdx.x * 256 + threadIdx.x) * 4;
  if (i >= n) return;
  float4 v = *(const float4*)(in + i);
  ushort4 o;
  o.x = f2bf(v.x); o.y = f2bf(v.y); o.z = f2bf(v.z); o.w = f2bf(v.w);
  *(ushort4*)(out + i) = o;
}

// ---------------- transpose fp32 (R x C) -> bf16 (C x R) ----------------
__global__ __launch_bounds__(256) void transpose_bf16_k(const float* __restrict__ in,
                                                        unsigned short* __restrict__ out,
                                                        int R, int C) {
  __shared__ float tile[32][33];
  int c0 = blockIdx.x * 32, r0 = blockIdx.y * 32;
  int tx = threadIdx.x, ty = threadIdx.y;
#pragma unroll
  for (int j = 0; j < 32; j += 8)
    tile[ty + j][tx] = in[(size_t)(r0 + ty + j) * C + c0 + tx];
  __syncthreads();
#pragma unroll
  for (int j = 0; j < 32; j += 8)
    out[(size_t)(c0 + ty + j) * R + r0 + tx] = f2bf(tile[tx][ty + j]);
}

// ---------------- GEMM C = A(MxK) @ B^T(NxK), bf16 in, 128x128 tile ----------------
// EPI==0: QKV epilogue -> Q (scaled 1/8) [bh][t][hd], K [bh][t][hd], V^T [bh][hd][t], bf16
// EPI==1: plain fp32 row-major C
template <int EPI>
__global__ __launch_bounds__(256) void gemm_bt_k(const unsigned short* __restrict__ A,
                                                 const unsigned short* __restrict__ Bt,
                                                 int M, int N, int K,
                                                 unsigned short* __restrict__ Qb,
                                                 unsigned short* __restrict__ Kb,
                                                 unsigned short* __restrict__ Vt,
                                                 float* __restrict__ Cout) {
  __shared__ unsigned short lA[128 * 32];
  __shared__ unsigned short lB[128 * 32];
  const int t = threadIdx.x;
  const int w = t >> 6, lane = t & 63;
  const int lr = lane & 15, lg = lane >> 4;
  const int wr = w >> 1, wc = w & 1;
  const int m0 = blockIdx.y * 128, n0 = blockIdx.x * 128;

  const f32x4 fzero = {0.f, 0.f, 0.f, 0.f};
  f32x4 acc[4][4];
#pragma unroll
  for (int mi = 0; mi < 4; ++mi)
#pragma unroll
    for (int ni = 0; ni < 4; ++ni) acc[mi][ni] = fzero;

  for (int k0 = 0; k0 < K; k0 += 32) {
    __syncthreads();
#pragma unroll
    for (int it = 0; it < 2; ++it) {
      int c = it * 256 + t;           // 16B chunk id
      int row = c >> 2, kc = (c & 3) * 8;
      int cb = it * 256 + w * 64;     // wave-uniform chunk base
      async_cp16((char*)lA + cb * 16, A + (size_t)(m0 + row) * K + k0 + kc);
      async_cp16((char*)lB + cb * 16, Bt + (size_t)(n0 + row) * K + k0 + kc);
    }
    __syncthreads();
    bf16x8 af[4], bf[4];
#pragma unroll
    for (int mi = 0; mi < 4; ++mi)
      af[mi] = *(const bf16x8*)&lA[(wr * 64 + mi * 16 + lr) * 32 + lg * 8];
#pragma unroll
    for (int ni = 0; ni < 4; ++ni)
      bf[ni] = *(const bf16x8*)&lB[(wc * 64 + ni * 16 + lr) * 32 + lg * 8];
#pragma unroll
    for (int mi = 0; mi < 4; ++mi)
#pragma unroll
      for (int ni = 0; ni < 4; ++ni)
        acc[mi][ni] = __builtin_amdgcn_mfma_f32_16x16x32_bf16(af[mi], bf[ni], acc[mi][ni], 0, 0, 0);
  }

#pragma unroll
  for (int mi = 0; mi < 4; ++mi) {
#pragma unroll
    for (int ni = 0; ni < 4; ++ni) {
      int gm = m0 + wr * 64 + mi * 16 + lg * 4;   // 4 consecutive rows
      int gn = n0 + wc * 64 + ni * 16 + lr;
      f32x4 v = acc[mi][ni];
      if (EPI == 0) {
        int b = gm >> 11, tt = gm & 2047;
        int sel = gn >> 10, rem = gn & 1023;
        int h = rem >> 6, hd = rem & 63;
        int bh = b * NHEAD + h;
        if (sel == 0) {
          unsigned short* p = Qb + ((size_t)bh * T_SEQ + tt) * HDIM + hd;
#pragma unroll
          for (int r = 0; r < 4; ++r) p[(size_t)r * HDIM] = f2bf(v[r] * 0.125f);
        } else if (sel == 1) {
          unsigned short* p = Kb + ((size_t)bh * T_SEQ + tt) * HDIM + hd;
#pragma unroll
          for (int r = 0; r < 4; ++r) p[(size_t)r * HDIM] = f2bf(v[r]);
        } else {
          ushort4 o;
          o.x = f2bf(v[0]); o.y = f2bf(v[1]); o.z = f2bf(v[2]); o.w = f2bf(v[3]);
          *(ushort4*)(Vt + ((size_t)bh * HDIM + hd) * T_SEQ + tt) = o;
        }
      } else {
#pragma unroll
        for (int r = 0; r < 4; ++r) Cout[(size_t)(gm + r) * N + gn] = v[r];
      }
    }
  }
}

// ---------------- causal flash attention fwd ----------------
// Q: [bh][t][hd] (pre-scaled by 1/8), K: [bh][t][hd], V^T: [bh][hd][t], out: [b][t][h*hd] bf16
__global__ __launch_bounds__(256) void attn_fwd_k(const unsigned short* __restrict__ Qb,
                                                  const unsigned short* __restrict__ Kb,
                                                  const unsigned short* __restrict__ Vt,
                                                  unsigned short* __restrict__ Ob) {
  __shared__ unsigned short lP[4][16 * 64];
  const int qt = blockIdx.x, bh = blockIdx.y;
  const int t = threadIdx.x;
  const int w = t >> 6, lane = t & 63;
  const int lr = lane & 15, lg = lane >> 4;
  const int q0 = qt * 64;
  const int qw = q0 + w * 16;   // this wave's q base
  unsigned short* lPw = lP[w];
  const unsigned short* Qp = Qb + (size_t)bh * T_SEQ * HDIM;
  const unsigned short* Kp = Kb + (size_t)bh * T_SEQ * HDIM;
  const unsigned short* Vp = Vt + (size_t)bh * HDIM * T_SEQ;

  bf16x8 qf[2];
#pragma unroll
  for (int ks = 0; ks < 2; ++ks)
    qf[ks] = *(const bf16x8*)(Qp + (size_t)(qw + lr) * HDIM + ks * 32 + lg * 8);

  const f32x4 fzero = {0.f, 0.f, 0.f, 0.f};
  f32x4 oacc[4];
#pragma unroll
  for (int nh = 0; nh < 4; ++nh) oacc[nh] = fzero;
  float mrow[4] = {-1e30f, -1e30f, -1e30f, -1e30f};
  float lrow[4] = {0.f, 0.f, 0.f, 0.f};

  for (int kv0 = 0; kv0 <= q0; kv0 += 64) {
    f32x4 s[4];
#pragma unroll
    for (int ni = 0; ni < 4; ++ni) s[ni] = fzero;
#pragma unroll
    for (int ni = 0; ni < 4; ++ni)
#pragma unroll
      for (int ks = 0; ks < 2; ++ks) {
        bf16x8 kf = *(const bf16x8*)(Kp + (size_t)(kv0 + ni * 16 + lr) * HDIM + ks * 32 + lg * 8);
        s[ni] = __builtin_amdgcn_mfma_f32_16x16x32_bf16(qf[ks], kf, s[ni], 0, 0, 0);
      }
    if (kv0 == q0) {   // diagonal tile: causal mask
#pragma unroll
      for (int ni = 0; ni < 4; ++ni) {
        int kvg = kv0 + ni * 16 + lr;
#pragma unroll
        for (int r = 0; r < 4; ++r) {
          int qg = qw + lg * 4 + r;
          if (kvg > qg) s[ni][r] = -1e30f;
        }
      }
    }
    float alpha[4];
#pragma unroll
    for (int r = 0; r < 4; ++r) {
      float pm = fmaxf(fmaxf(s[0][r], s[1][r]), fmaxf(s[2][r], s[3][r]));
#pragma unroll
      for (int msk = 1; msk < 16; msk <<= 1) pm = fmaxf(pm, __shfl_xor(pm, msk, 64));
      float mn = fmaxf(mrow[r], pm);
      alpha[r] = __expf(mrow[r] - mn);
      mrow[r] = mn;
      float rs = 0.f;
#pragma unroll
      for (int ni = 0; ni < 4; ++ni) {
        float p = __expf(s[ni][r] - mn);
        s[ni][r] = p;
        rs += p;
      }
#pragma unroll
      for (int msk = 1; msk < 16; msk <<= 1) rs += __shfl_xor(rs, msk, 64);
      lrow[r] = lrow[r] * alpha[r] + rs;
    }
#pragma unroll
    for (int nh = 0; nh < 4; ++nh)
#pragma unroll
      for (int r = 0; r < 4; ++r) oacc[nh][r] *= alpha[r];
    // P -> per-wave LDS to re-fragment for PV
#pragma unroll
    for (int ni = 0; ni < 4; ++ni)
#pragma unroll
      for (int r = 0; r < 4; ++r)
        lPw[(lg * 4 + r) * 64 + ni * 16 + lr] = f2bf(s[ni][r]);
    bf16x8 pf[2];
#pragma unroll
    for (int ks = 0; ks < 2; ++ks)
      pf[ks] = *(const bf16x8*)&lPw[lr * 64 + ks * 32 + lg * 8];
#pragma unroll
    for (int nh = 0; nh < 4; ++nh)
#pragma unroll
      for (int ks = 0; ks < 2; ++ks) {
        bf16x8 vf = *(const bf16x8*)(Vp + (size_t)(nh * 16 + lr) * T_SEQ + kv0 + ks * 32 + lg * 8);
        oacc[nh] = __builtin_amdgcn_mfma_f32_16x16x32_bf16(pf[ks], vf, oacc[nh], 0, 0, 0);
      }
  }
  const int b = bh >> 4, h = bh & 15;
  float inv[4];
#pragma unroll
  for (int r = 0; r < 4; ++r) inv[r] = 1.f / lrow[r];
#pragma unroll
  for (int nh = 0; nh < 4; ++nh)
#pragma unroll
    for (int r = 0; r < 4; ++r)
      Ob[(size_t)(b * T_SEQ + qw + lg * 4 + r) * DMODEL + h * HDIM + nh * 16 + lr] =
          f2bf(oacc[nh][r] * inv[r]);
}

extern "C" void kernel_launch(void* const* d_in, const int* in_sizes, int n_in,
                              void* d_out, int out_size, void* d_ws, size_t ws_size,
                              hipStream_t stream) {
  const float* x = (const float*)d_in[0];
  const float* Wqkv = (const float*)d_in[1];
  const float* Wout = (const float*)d_in[2];
  float* out = (float*)d_out;

  unsigned short* ws = (unsigned short*)d_ws;
  const size_t nx = (size_t)NBATCH * T_SEQ * DMODEL;   // 8388608 tokens*channels
  unsigned short* xb    = ws;
  unsigned short* wqkvT = xb + nx;
  unsigned short* woutT = wqkvT + (size_t)3 * DMODEL * DMODEL;
  unsigned short* Qb    = woutT + (size_t)DMODEL * DMODEL;
  unsigned short* Kb    = Qb + nx;
  unsigned short* Vt    = Kb + nx;
  unsigned short* Ab    = Vt + nx;
  size_t need = 2ull * (5 * nx + 4ull * DMODEL * DMODEL);   // ~92.3 MB
  if (ws_size < need) return;

  conv_bf16_k<<<dim3((unsigned)(nx / 1024)), dim3(256), 0, stream>>>(x, xb, (int)nx);
  transpose_bf16_k<<<dim3(3 * DMODEL / 32, DMODEL / 32), dim3(32, 8), 0, stream>>>(
      Wqkv, wqkvT, DMODEL, 3 * DMODEL);
  transpose_bf16_k<<<dim3(DMODEL / 32, DMODEL / 32), dim3(32, 8), 0, stream>>>(
      Wout, woutT, DMODEL, DMODEL);
  gemm_bt_k<0><<<dim3(3 * DMODEL / 128, NBATCH * T_SEQ / 128), dim3(256), 0, stream>>>(
      xb, wqkvT, NBATCH * T_SEQ, 3 * DMODEL, DMODEL, Qb, Kb, Vt, nullptr);
  attn_fwd_k<<<dim3(T_SEQ / 64, NBATCH * NHEAD), dim3(256), 0, stream>>>(Qb, Kb, Vt, Ab);
  gemm_bt_k<1><<<dim3(DMODEL / 128, NBATCH * T_SEQ / 128), dim3(256), 0, stream>>>(
      Ab, woutT, NBATCH * T_SEQ, DMODEL, DMODEL, nullptr, nullptr, nullptr, out);
}

// Round 3
// 312.421 us; speedup vs baseline: 1.8248x; 1.8248x over previous
//
#include <hip/hip_runtime.h>
#include <hip/hip_bf16.h>

#define T_SEQ 2048
#define NBATCH 4
#define NHEAD 16
#define HDIM 64
#define DMODEL 1024

typedef __bf16 bf16x8 __attribute__((ext_vector_type(8)));
typedef float f32x4 __attribute__((ext_vector_type(4)));
typedef float f32x16 __attribute__((ext_vector_type(16)));

__device__ __forceinline__ unsigned short f2bf(float f) {
  unsigned int u = __builtin_bit_cast(unsigned int, f);
  u += 0x7fffu + ((u >> 16) & 1u);
  return (unsigned short)(u >> 16);
}

__device__ __forceinline__ void async_cp16(void* lds, const void* g) {
  __builtin_amdgcn_global_load_lds((const __attribute__((address_space(1))) void*)g,
                                   (__attribute__((address_space(3))) void*)lds,
                                   16, 0, 0);
}

// ---------------- fp32 -> bf16 convert (vectorized) ----------------
__global__ __launch_bounds__(256) void conv_bf16_k(const float* __restrict__ in,
                                                   unsigned short* __restrict__ out, int n) {
  int i = (blockIdx.x * 256 + threadIdx.x) * 4;
  if (i >= n) return;
  float4 v = *(const float4*)(in + i);
  ushort4 o;
  o.x = f2bf(v.x); o.y = f2bf(v.y); o.z = f2bf(v.z); o.w = f2bf(v.w);
  *(ushort4*)(out + i) = o;
}

// ---------------- transpose fp32 (R x C) -> bf16 (C x R) ----------------
__global__ __launch_bounds__(256) void transpose_bf16_k(const float* __restrict__ in,
                                                        unsigned short* __restrict__ out,
                                                        int R, int C) {
  __shared__ float tile[32][33];
  int c0 = blockIdx.x * 32, r0 = blockIdx.y * 32;
  int tx = threadIdx.x, ty = threadIdx.y;
#pragma unroll
  for (int j = 0; j < 32; j += 8)
    tile[ty + j][tx] = in[(size_t)(r0 + ty + j) * C + c0 + tx];
  __syncthreads();
#pragma unroll
  for (int j = 0; j < 32; j += 8)
    out[(size_t)(c0 + ty + j) * R + r0 + tx] = f2bf(tile[tx][ty + j]);
}

// ---------------- GEMM C = A(MxK) @ B^T(NxK), bf16 in, 128x128 tile ----------------
// EPI==0: QKV epilogue -> Q (scaled 1/8) [bh][t][hd], K [bh][t][hd], V^T [bh][hd][t], bf16
// EPI==1: plain fp32 row-major C
template <int EPI>
__global__ __launch_bounds__(256) void gemm_bt_k(const unsigned short* __restrict__ A,
                                                 const unsigned short* __restrict__ Bt,
                                                 int M, int N, int K,
                                                 unsigned short* __restrict__ Qb,
                                                 unsigned short* __restrict__ Kb,
                                                 unsigned short* __restrict__ Vt,
                                                 float* __restrict__ Cout) {
  __shared__ unsigned short lA[128 * 32];
  __shared__ unsigned short lB[128 * 32];
  const int t = threadIdx.x;
  const int w = t >> 6, lane = t & 63;
  const int lr = lane & 15, lg = lane >> 4;
  const int wr = w >> 1, wc = w & 1;
  const int m0 = blockIdx.y * 128, n0 = blockIdx.x * 128;

  const f32x4 fzero = {0.f, 0.f, 0.f, 0.f};
  f32x4 acc[4][4];
#pragma unroll
  for (int mi = 0; mi < 4; ++mi)
#pragma unroll
    for (int ni = 0; ni < 4; ++ni) acc[mi][ni] = fzero;

  for (int k0 = 0; k0 < K; k0 += 32) {
    __syncthreads();
#pragma unroll
    for (int it = 0; it < 2; ++it) {
      int c = it * 256 + t;           // 16B chunk id
      int row = c >> 2, kc = (c & 3) * 8;
      int cb = it * 256 + w * 64;     // wave-uniform chunk base
      async_cp16((char*)lA + cb * 16, A + (size_t)(m0 + row) * K + k0 + kc);
      async_cp16((char*)lB + cb * 16, Bt + (size_t)(n0 + row) * K + k0 + kc);
    }
    __syncthreads();
    bf16x8 af[4], bf[4];
#pragma unroll
    for (int mi = 0; mi < 4; ++mi)
      af[mi] = *(const bf16x8*)&lA[(wr * 64 + mi * 16 + lr) * 32 + lg * 8];
#pragma unroll
    for (int ni = 0; ni < 4; ++ni)
      bf[ni] = *(const bf16x8*)&lB[(wc * 64 + ni * 16 + lr) * 32 + lg * 8];
#pragma unroll
    for (int mi = 0; mi < 4; ++mi)
#pragma unroll
      for (int ni = 0; ni < 4; ++ni)
        acc[mi][ni] = __builtin_amdgcn_mfma_f32_16x16x32_bf16(af[mi], bf[ni], acc[mi][ni], 0, 0, 0);
  }

#pragma unroll
  for (int mi = 0; mi < 4; ++mi) {
#pragma unroll
    for (int ni = 0; ni < 4; ++ni) {
      int gm = m0 + wr * 64 + mi * 16 + lg * 4;   // 4 consecutive rows
      int gn = n0 + wc * 64 + ni * 16 + lr;
      f32x4 v = acc[mi][ni];
      if (EPI == 0) {
        int b = gm >> 11, tt = gm & 2047;
        int sel = gn >> 10, rem = gn & 1023;
        int h = rem >> 6, hd = rem & 63;
        int bh = b * NHEAD + h;
        if (sel == 0) {
          unsigned short* p = Qb + ((size_t)bh * T_SEQ + tt) * HDIM + hd;
#pragma unroll
          for (int r = 0; r < 4; ++r) p[(size_t)r * HDIM] = f2bf(v[r] * 0.125f);
        } else if (sel == 1) {
          unsigned short* p = Kb + ((size_t)bh * T_SEQ + tt) * HDIM + hd;
#pragma unroll
          for (int r = 0; r < 4; ++r) p[(size_t)r * HDIM] = f2bf(v[r]);
        } else {
          ushort4 o;
          o.x = f2bf(v[0]); o.y = f2bf(v[1]); o.z = f2bf(v[2]); o.w = f2bf(v[3]);
          *(ushort4*)(Vt + ((size_t)bh * HDIM + hd) * T_SEQ + tt) = o;
        }
      } else {
#pragma unroll
        for (int r = 0; r < 4; ++r) Cout[(size_t)(gm + r) * N + gn] = v[r];
      }
    }
  }
}

// ---------------- causal flash attention fwd, v3 (overflow-proof softmax) -------
// One wave per 32 q-rows. Swapped QK^T: S^T = mfma(K, Q) so lane owns q=lane&31.
// Swapped PV: O^T = mfma(V^T, P^T) so O cols stay q=lane&31 (per-lane scalar rescale).
// Plain online softmax (exp arg <= 0 per-lane structurally); finite mask -30000.
__global__ __launch_bounds__(64) void attn_fwd3_k(const unsigned short* __restrict__ Qb,
                                                  const unsigned short* __restrict__ Kb,
                                                  const unsigned short* __restrict__ Vt,
                                                  unsigned short* __restrict__ Ob) {
  const int qb = (int)gridDim.x - 1 - (int)blockIdx.x;   // heavy blocks dispatch first
  const int bh = blockIdx.y;
  const int lane = threadIdx.x;
  const int lq = lane & 31;        // this lane's q column (and hd row for PV-A)
  const int hi = lane >> 5;
  const int qw = qb * 32;
  const unsigned short* Qp = Qb + (size_t)bh * T_SEQ * HDIM;
  const unsigned short* Kp = Kb + (size_t)bh * T_SEQ * HDIM;
  const unsigned short* Vp = Vt + (size_t)bh * HDIM * T_SEQ;

  // Q B-fragments (col=q=lq, k-slot = hi*8+j within each d-chunk of 16)
  bf16x8 qf[4];
#pragma unroll
  for (int dj = 0; dj < 4; ++dj)
    qf[dj] = *(const bf16x8*)(Qp + (size_t)(qw + lq) * HDIM + dj * 16 + hi * 8);

  f32x16 O0, O1;
#pragma unroll
  for (int r = 0; r < 16; ++r) { O0[r] = 0.f; O1[r] = 0.f; }
  float m_run = -30000.0f, l_run = 0.f;

  const unsigned short* Kl = Kp + (size_t)lq * HDIM + hi * 8;       // + kv0*HDIM + dj*16
  const unsigned short* Vl0 = Vp + (size_t)lq * T_SEQ + hi * 8;     // + kv0 + jj*16
  const unsigned short* Vl1 = Vp + (size_t)(lq + 32) * T_SEQ + hi * 8;

  const int nblk = qb + 1;
  for (int i = 0; i < nblk; ++i) {
    const int kv0 = i * 32;
    // ---- S^T = K_tile . Q^T  (D[kv][q], col=q=lq) ----
    f32x16 S;
#pragma unroll
    for (int r = 0; r < 16; ++r) S[r] = 0.f;
#pragma unroll
    for (int dj = 0; dj < 4; ++dj) {
      bf16x8 kf = *(const bf16x8*)(Kl + (size_t)kv0 * HDIM + dj * 16);
      S = __builtin_amdgcn_mfma_f32_32x32x16_bf16(kf, qf[dj], S, 0, 0, 0);
    }
    // ---- causal mask (diagonal block only): kv_local = (r&3)+8*(r>>2)+4*hi ----
    if (i == nblk - 1) {
#pragma unroll
      for (int r = 0; r < 16; ++r) {
        int kvl = (r & 3) + 8 * (r >> 2) + 4 * hi;
        S[r] = (kvl > lq) ? -30000.0f : S[r];
      }
    }
    // ---- row max: in-lane 16 + cross-half via shfl_xor (bulletproof) ----
    float pmax = S[0];
#pragma unroll
    for (int r = 1; r < 16; ++r) pmax = fmaxf(pmax, S[r]);
    pmax = fmaxf(pmax, __shfl_xor(pmax, 32, 64));
    // ---- plain online rescale: exp args <= 0 always ----
    float mn = fmaxf(m_run, pmax);
    float al = __expf(m_run - mn);
    m_run = mn;
    // ---- p = exp(S - m), row sum ----
    float ps = 0.f;
#pragma unroll
    for (int r = 0; r < 16; ++r) {
      S[r] = __expf(S[r] - mn);
      ps += S[r];
    }
    ps += __shfl_xor(ps, 32, 64);
    l_run = l_run * al + ps;
#pragma unroll
    for (int r = 0; r < 16; ++r) { O0[r] *= al; O1[r] *= al; }
    // ---- P^T B-fragments via cvt_pk + permlane32_swap, then PV ----
#pragma unroll
    for (int jj = 0; jj < 2; ++jj) {
      unsigned w0, w1, w2, w3;
      asm("v_cvt_pk_bf16_f32 %0, %1, %2" : "=v"(w0) : "v"(S[8 * jj + 0]), "v"(S[8 * jj + 1]));
      asm("v_cvt_pk_bf16_f32 %0, %1, %2" : "=v"(w1) : "v"(S[8 * jj + 2]), "v"(S[8 * jj + 3]));
      asm("v_cvt_pk_bf16_f32 %0, %1, %2" : "=v"(w2) : "v"(S[8 * jj + 4]), "v"(S[8 * jj + 5]));
      asm("v_cvt_pk_bf16_f32 %0, %1, %2" : "=v"(w3) : "v"(S[8 * jj + 6]), "v"(S[8 * jj + 7]));
      asm("v_permlane32_swap_b32 %0, %1" : "+v"(w0), "+v"(w2));
      asm("v_permlane32_swap_b32 %0, %1" : "+v"(w1), "+v"(w3));
      union { unsigned u[4]; bf16x8 v; } pf;
      pf.u[0] = w0; pf.u[1] = w1; pf.u[2] = w2; pf.u[3] = w3;
      bf16x8 vf0 = *(const bf16x8*)(Vl0 + kv0 + jj * 16);
      bf16x8 vf1 = *(const bf16x8*)(Vl1 + kv0 + jj * 16);
      O0 = __builtin_amdgcn_mfma_f32_32x32x16_bf16(vf0, pf.v, O0, 0, 0, 0);
      O1 = __builtin_amdgcn_mfma_f32_32x32x16_bf16(vf1, pf.v, O1, 0, 0, 0);
    }
  }
  // ---- epilogue: O^T cols are q=lq; rows hd = (r&3)+8*(r>>2)+4*hi (+32 for O1) ----
  const int b = bh >> 4, h = bh & 15;
  const float linv = 1.0f / l_run;
  unsigned short* op = Ob + ((size_t)(b * T_SEQ + qw + lq)) * DMODEL + h * HDIM;
#pragma unroll
  for (int g = 0; g < 4; ++g) {
    ushort4 o;
    o.x = f2bf(O0[4 * g + 0] * linv);
    o.y = f2bf(O0[4 * g + 1] * linv);
    o.z = f2bf(O0[4 * g + 2] * linv);
    o.w = f2bf(O0[4 * g + 3] * linv);
    *(ushort4*)(op + 8 * g + 4 * hi) = o;
    ushort4 o2;
    o2.x = f2bf(O1[4 * g + 0] * linv);
    o2.y = f2bf(O1[4 * g + 1] * linv);
    o2.z = f2bf(O1[4 * g + 2] * linv);
    o2.w = f2bf(O1[4 * g + 3] * linv);
    *(ushort4*)(op + 32 + 8 * g + 4 * hi) = o2;
  }
}

extern "C" void kernel_launch(void* const* d_in, const int* in_sizes, int n_in,
                              void* d_out, int out_size, void* d_ws, size_t ws_size,
                              hipStream_t stream) {
  const float* x = (const float*)d_in[0];
  const float* Wqkv = (const float*)d_in[1];
  const float* Wout = (const float*)d_in[2];
  float* out = (float*)d_out;

  unsigned short* ws = (unsigned short*)d_ws;
  const size_t nx = (size_t)NBATCH * T_SEQ * DMODEL;   // 8388608 tokens*channels
  unsigned short* xb    = ws;
  unsigned short* wqkvT = xb + nx;
  unsigned short* woutT = wqkvT + (size_t)3 * DMODEL * DMODEL;
  unsigned short* Qb    = woutT + (size_t)DMODEL * DMODEL;
  unsigned short* Kb    = Qb + nx;
  unsigned short* Vt    = Kb + nx;
  unsigned short* Ab    = Vt + nx;
  size_t need = 2ull * (5 * nx + 4ull * DMODEL * DMODEL);   // ~92.3 MB
  if (ws_size < need) return;

  conv_bf16_k<<<dim3((unsigned)(nx / 1024)), dim3(256), 0, stream>>>(x, xb, (int)nx);
  transpose_bf16_k<<<dim3(3 * DMODEL / 32, DMODEL / 32), dim3(32, 8), 0, stream>>>(
      Wqkv, wqkvT, DMODEL, 3 * DMODEL);
  transpose_bf16_k<<<dim3(DMODEL / 32, DMODEL / 32), dim3(32, 8), 0, stream>>>(
      Wout, woutT, DMODEL, DMODEL);
  gemm_bt_k<0><<<dim3(3 * DMODEL / 128, NBATCH * T_SEQ / 128), dim3(256), 0, stream>>>(
      xb, wqkvT, NBATCH * T_SEQ, 3 * DMODEL, DMODEL, Qb, Kb, Vt, nullptr);
  attn_fwd3_k<<<dim3(T_SEQ / 32, NBATCH * NHEAD), dim3(64), 0, stream>>>(Qb, Kb, Vt, Ab);
  gemm_bt_k<1><<<dim3(DMODEL / 128, NBATCH * T_SEQ / 128), dim3(256), 0, stream>>>(
      Ab, woutT, NBATCH * T_SEQ, DMODEL, DMODEL, nullptr, nullptr, nullptr, out);
}